// Round 4
// baseline (491.028 us; speedup 1.0000x reference)
//
#include <hip/hip_runtime.h>
#include <cmath>

typedef unsigned long long u64;
typedef unsigned int u32;
typedef unsigned char u8;

#define DHID 256
#define SORTN 8192
#define NMAX 100000
#define EMAX 3200000
#define NBLKMAX 128

// -------- all scratch as device globals: d_ws is NOT used --------
__device__ float g_srow[NMAX];
__device__ float g_scol[NMAX];
__device__ int   g_destC[NMAX];
__device__ int   g_destF[NMAX];
__device__ u8    g_selC[NMAX];
__device__ u8    g_selF[NMAX];
__device__ u8    g_mask[EMAX];
__device__ float g_pmin[1024];
__device__ float g_pmax[1024];
__device__ float g_fmm[2];
__device__ int   g_blkC[NBLKMAX];
__device__ int   g_blkF[NBLKMAX];
__device__ int   g_tot[2];

// ---------------- K0: zero sel flags ----------------
__global__ void k_zero(int N){
  int i = blockIdx.x*256 + threadIdx.x;
  if (i < N){ g_selC[i] = 0; g_selF[i] = 0; }
}

// ---------------- K1: per-node scores (wave per node, f64 accum) ------------
__global__ void k_node_scores(const float* __restrict__ x, const float* __restrict__ W, int N){
  int lane = threadIdx.x & 63, wave = threadIdx.x >> 6;
  int n = blockIdx.x*4 + wave;
  if (n >= N) return;
  float4 xv = ((const float4*)(x + (size_t)n*DHID))[lane];
  float4 wr = ((const float4*)W)[lane];
  float4 wc = ((const float4*)W)[64 + lane];
  double dr = (double)xv.x*wr.x + (double)xv.y*wr.y + (double)xv.z*wr.z + (double)xv.w*wr.w;
  double dc = (double)xv.x*wc.x + (double)xv.y*wc.y + (double)xv.z*wc.z + (double)xv.w*wc.w;
  #pragma unroll
  for (int off = 32; off; off >>= 1){
    dr += __shfl_xor(dr, off);
    dc += __shfl_xor(dc, off);
  }
  if (lane == 0){ g_srow[n] = (float)dr; g_scol[n] = (float)dc; }
}

// ---------------- K2: global min/max partials over recomputed edge scores ----
__global__ void k_minmax_part(const int* __restrict__ ei, const float* __restrict__ b, int E){
  float b0 = b[0];
  float lmin = INFINITY, lmax = -INFINITY;
  for (int e = blockIdx.x*256 + threadIdx.x; e < E; e += gridDim.x*256){
    int r = ei[e], c = ei[E + e];
    float s = (g_srow[r] + g_scol[c]) + b0;
    lmin = fminf(lmin, s); lmax = fmaxf(lmax, s);
  }
  __shared__ float smin[256], smax[256];
  smin[threadIdx.x] = lmin; smax[threadIdx.x] = lmax;
  __syncthreads();
  for (int st = 128; st; st >>= 1){
    if (threadIdx.x < st){
      smin[threadIdx.x] = fminf(smin[threadIdx.x], smin[threadIdx.x+st]);
      smax[threadIdx.x] = fmaxf(smax[threadIdx.x], smax[threadIdx.x+st]);
    }
    __syncthreads();
  }
  if (threadIdx.x == 0){ g_pmin[blockIdx.x] = smin[0]; g_pmax[blockIdx.x] = smax[0]; }
}

// ---------------- K3: reduce partials ----------------
__global__ void k_minmax_final(int nb){
  float lmin = INFINITY, lmax = -INFINITY;
  for (int i = threadIdx.x; i < nb; i += 256){
    lmin = fminf(lmin, g_pmin[i]); lmax = fmaxf(lmax, g_pmax[i]);
  }
  __shared__ float smin[256], smax[256];
  smin[threadIdx.x] = lmin; smax[threadIdx.x] = lmax;
  __syncthreads();
  for (int st = 128; st; st >>= 1){
    if (threadIdx.x < st){
      smin[threadIdx.x] = fminf(smin[threadIdx.x], smin[threadIdx.x+st]);
      smax[threadIdx.x] = fmaxf(smax[threadIdx.x], smax[threadIdx.x+st]);
    }
    __syncthreads();
  }
  if (threadIdx.x == 0){ g_fmm[0] = smin[0]; g_fmm[1] = smax[0]; }
}

// ---------------- K4: per-graph stable top-k (bitonic, 64KB LDS) ------------
// key = (~orderable(norm) << 32) | idx -> ascending == (norm desc, idx asc),
// matching jnp.argsort(-norm) stable semantics incl. f32 quantization ties.
__global__ __launch_bounds__(256) void k_topk(const int* __restrict__ ei,
    const float* __restrict__ b, int E, int EPG, int k){
  __shared__ u64 K[SORTN];
  int g = blockIdx.x;
  long long base = (long long)g * EPG;
  float b0 = b[0];
  float fmin = g_fmm[0], fmax = g_fmm[1];
  float denom = (fmax - fmin) + 1e-12f;
  float gf = (float)g;
  for (int i = threadIdx.x; i < SORTN; i += 256){
    u64 key = ~0ull;
    if (i < EPG){
      long long e = base + i;
      int r = ei[e], c = ei[E + e];
      float s = (g_srow[r] + g_scol[c]) + b0;  // same f32 expr everywhere
      float frac = (s - fmin) / denom;         // f32 divide, as reference
      float nk = frac - gf;                    // f32 subtract -> same quantization
      u32 u = __float_as_uint(nk);
      u = (u & 0x80000000u) ? ~u : (u | 0x80000000u);  // orderable ascending
      u = ~u;                                          // descending
      key = ((u64)u << 32) | (u32)i;
    }
    K[i] = key;
  }
  for (int size = 2; size <= SORTN; size <<= 1){
    for (int stride = size >> 1; stride > 0; stride >>= 1){
      __syncthreads();
      for (int i = threadIdx.x; i < SORTN; i += 256){
        int j = i ^ stride;
        if (j > i){
          u64 a = K[i], bb = K[j];
          bool asc = ((i & size) == 0);
          if ((a > bb) == asc){ K[i] = bb; K[j] = a; }
        }
      }
    }
  }
  __syncthreads();
  for (int i = threadIdx.x; i < SORTN; i += 256){
    u64 key = K[i];
    if (key != ~0ull){
      int idx = (int)(key & 0xFFFFFFFFull);
      long long e = base + idx;
      int r = ei[e], c = ei[E + e];
      int kept = (i < k);
      g_mask[e] = (u8)kept;
      if (kept){ g_selC[r] = 1; g_selC[c] = 1; }
      else     { g_selF[r] = 1; g_selF[c] = 1; }
    }
  }
}

// ---------------- K5: per-1024-node block sums of sel flags ----------------
__global__ void k_blocksum(int N){
  int bb = blockIdx.x, tid = threadIdx.x;
  int start = bb*1024;
  int c = 0, f = 0;
  #pragma unroll
  for (int q = 0; q < 4; q++){
    int n = start + tid*4 + q;
    if (n < N){ c += g_selC[n]; f += g_selF[n]; }
  }
  __shared__ int sc[256], sf[256];
  sc[tid] = c; sf[tid] = f;
  __syncthreads();
  for (int st = 128; st; st >>= 1){
    if (tid < st){ sc[tid] += sc[tid+st]; sf[tid] += sf[tid+st]; }
    __syncthreads();
  }
  if (tid == 0){ g_blkC[bb] = sc[0]; g_blkF[bb] = sf[0]; }
}

// ---------------- K6: serial scan of block sums + counts out ----------------
__global__ void k_scanblk(int nb, float* __restrict__ out, long long oNC, long long oNF){
  if (blockIdx.x == 0 && threadIdx.x == 0){
    int accC = 0, accF = 0;
    for (int i = 0; i < nb; i++){
      int c = g_blkC[i], f = g_blkF[i];
      g_blkC[i] = accC; g_blkF[i] = accF;
      accC += c; accF += f;
    }
    g_tot[0] = accC; g_tot[1] = accF;
    out[oNC] = (float)accC;
    out[oNF] = (float)accF;
  }
}

// ---------------- K7: dest permutation + batch outputs ----------------
__global__ void k_dest(const int* __restrict__ batch,
    float* __restrict__ out, long long oCB, long long oFB, int N){
  int bb = blockIdx.x, tid = threadIdx.x;
  int start = bb*1024;
  int idx0 = start + tid*4;
  int c[4], f[4]; int sc = 0, sf = 0;
  #pragma unroll
  for (int q = 0; q < 4; q++){
    int n = idx0 + q;
    int vc = (n < N) ? (int)g_selC[n] : 0;
    int vf = (n < N) ? (int)g_selF[n] : 0;
    c[q] = vc; f[q] = vf; sc += vc; sf += vf;
  }
  __shared__ int xc[256], xf[256];
  xc[tid] = sc; xf[tid] = sf;
  __syncthreads();
  for (int st = 1; st < 256; st <<= 1){
    int ac = (tid >= st) ? xc[tid-st] : 0;
    int af = (tid >= st) ? xf[tid-st] : 0;
    __syncthreads();
    xc[tid] += ac; xf[tid] += af;
    __syncthreads();
  }
  int excC = ((tid ? xc[tid-1] : 0)) + g_blkC[bb];
  int excF = ((tid ? xf[tid-1] : 0)) + g_blkF[bb];
  int nC = g_tot[0], nF = g_tot[1];
  int runC = 0, runF = 0;
  #pragma unroll
  for (int q = 0; q < 4; q++){
    int n = idx0 + q;
    if (n >= N) break;
    runC += c[q]; runF += f[q];
    int cumC = excC + runC;   // inclusive selected count through n
    int cumF = excF + runF;
    int dC = c[q] ? (cumC - 1) : (nC + (n - cumC));
    int dF = f[q] ? (cumF - 1) : (nF + (n - cumF));
    dC = min(max(dC, 0), N-1);  // firewall
    dF = min(max(dF, 0), N-1);
    g_destC[n] = dC; g_destF[n] = dF;
    float bt = (float)batch[n];
    out[oCB + dC] = c[q] ? bt : -1.0f;
    out[oFB + dF] = f[q] ? bt : -1.0f;
  }
}

// ---------------- K8: edge outputs (all f32) ----------------
__global__ void k_edges_out(const int* __restrict__ ei, const float* __restrict__ b,
    float* __restrict__ out, long long oCE, long long oCW, long long oFE, long long oFW,
    long long oS, long long oM, int E){
  int e = blockIdx.x*256 + threadIdx.x;
  if (e >= E) return;
  int r = ei[e], c = ei[E + e];
  float s = (g_srow[r] + g_scol[c]) + b[0];
  int m = g_mask[e];
  out[oCE + e]     = m ? (float)g_destC[r] : -1.0f;
  out[oCE + E + e] = m ? (float)g_destC[c] : -1.0f;
  out[oCW + e]     = m ? s : 0.0f;
  out[oFE + e]     = m ? -1.0f : (float)g_destF[r];
  out[oFE + E + e] = m ? -1.0f : (float)g_destF[c];
  out[oFW + e]     = m ? 0.0f : -s;
  out[oS + e]      = s;
  out[oM + e]      = m ? 1.0f : 0.0f;
}

// ---------------- K9: x permutation scatter (f32 passthrough) ----------------
__global__ void k_x_out(const float* __restrict__ x, float* __restrict__ out,
    long long oCX, long long oFX, int N){
  long long t = (long long)blockIdx.x*256 + threadIdx.x;
  if (t >= (long long)N*64) return;
  int n = (int)(t >> 6), cq = (int)(t & 63);
  float4 v = ((const float4*)x)[(long long)n*64 + cq];
  int dC = g_destC[n], dF = g_destF[n];
  long long iC = oCX + (long long)dC*DHID + cq*4;   // oCX==0 -> 16B aligned
  *reinterpret_cast<float4*>(out + iC) = v;
  long long iF = oFX + (long long)dF*DHID + cq*4;   // odd base -> scalar stores
  out[iF+0] = v.x; out[iF+1] = v.y; out[iF+2] = v.z; out[iF+3] = v.w;
}

extern "C" void kernel_launch(void* const* d_in, const int* in_sizes, int n_in,
                              void* d_out, int out_size, void* d_ws, size_t ws_size,
                              hipStream_t stream) {
  const float* x   = (const float*)d_in[0];
  const int* ei    = (const int*)d_in[1];
  const int* batch = (const int*)d_in[2];
  const float* W   = (const float*)d_in[3];
  const float* b   = (const float*)d_in[4];
  float* out = (float*)d_out;

  int N   = in_sizes[0] / DHID;   // 100000
  int E   = in_sizes[1] / 2;      // 3200000
  if (N > NMAX) N = NMAX;
  if (E > EMAX) E = EMAX;
  const int G   = N / 200;              // 500
  const int EPG = (G > 0) ? E / G : 0;  // 6400
  const int k   = (int)ceilf(0.8f * (float)EPG);  // 5120 (f32 semantics match ref)

  // ---- output offsets (f32 elements, reference return order) ----
  long long oCX = 0;
  long long oCE = oCX + (long long)N*DHID;  // 25,600,000
  long long oCW = oCE + 2LL*E;              // 32,000,000
  long long oCB = oCW + E;                  // 35,200,000
  long long oNC = oCB + N;                  // 35,300,000
  long long oFX = oNC + 1;                  // 35,300,001
  long long oFE = oFX + (long long)N*DHID;  // 60,900,001
  long long oFW = oFE + 2LL*E;              // 67,300,001
  long long oFB = oFW + E;                  // 70,500,001
  long long oNF = oFB + N;                  // 70,600,001
  long long oS  = oNF + 1;                  // 70,600,002
  long long oM  = oS + E;                   // 73,800,002

  k_zero<<<(N + 255)/256, 256, 0, stream>>>(N);
  k_node_scores<<<(N + 3)/4, 256, 0, stream>>>(x, W, N);
  k_minmax_part<<<1024, 256, 0, stream>>>(ei, b, E);
  k_minmax_final<<<1, 256, 0, stream>>>(1024);
  k_topk<<<G, 256, 0, stream>>>(ei, b, E, EPG, k);
  int nblk = (N + 1023)/1024;
  k_blocksum<<<nblk, 256, 0, stream>>>(N);
  k_scanblk<<<1, 64, 0, stream>>>(nblk, out, oNC, oNF);
  k_dest<<<nblk, 256, 0, stream>>>(batch, out, oCB, oFB, N);
  k_edges_out<<<(E + 255)/256, 256, 0, stream>>>(ei, b, out, oCE, oCW, oFE, oFW, oS, oM, E);
  k_x_out<<<(int)(((long long)N*64 + 255)/256), 256, 0, stream>>>(x, out, oCX, oFX, N);
}

// Round 5
// 231.828 us; speedup vs baseline: 2.1181x; 2.1181x over previous
//
#include <hip/hip_runtime.h>
#include <cmath>

typedef unsigned long long u64;
typedef unsigned int u32;
typedef unsigned char u8;

#define DHID 256
#define NMAX 100000
#define EMAX 3200000
#define EPGMAX 6400
#define NBLKMAX 128

// -------- all scratch as device globals: d_ws is NOT used --------
__device__ float g_srow[NMAX];
__device__ float g_scol[NMAX];
__device__ int   g_destC[NMAX];
__device__ int   g_destF[NMAX];
__device__ u8    g_selC[NMAX];
__device__ u8    g_selF[NMAX];
__device__ u8    g_mask[EMAX];
__device__ float g_pmin[1024];
__device__ float g_pmax[1024];
__device__ float g_fmm[2];
__device__ int   g_blkC[NBLKMAX];
__device__ int   g_blkF[NBLKMAX];
__device__ int   g_tot[2];

// ---------------- K0: zero sel flags ----------------
__global__ void k_zero(int N){
  int i = blockIdx.x*256 + threadIdx.x;
  if (i < N){ g_selC[i] = 0; g_selF[i] = 0; }
}

// ---------------- K1: per-node scores (wave per node, f64 accum) ------------
__global__ void k_node_scores(const float* __restrict__ x, const float* __restrict__ W, int N){
  int lane = threadIdx.x & 63, wave = threadIdx.x >> 6;
  int n = blockIdx.x*4 + wave;
  if (n >= N) return;
  float4 xv = ((const float4*)(x + (size_t)n*DHID))[lane];
  float4 wr = ((const float4*)W)[lane];
  float4 wc = ((const float4*)W)[64 + lane];
  double dr = (double)xv.x*wr.x + (double)xv.y*wr.y + (double)xv.z*wr.z + (double)xv.w*wr.w;
  double dc = (double)xv.x*wc.x + (double)xv.y*wc.y + (double)xv.z*wc.z + (double)xv.w*wc.w;
  #pragma unroll
  for (int off = 32; off; off >>= 1){
    dr += __shfl_xor(dr, off);
    dc += __shfl_xor(dc, off);
  }
  if (lane == 0){ g_srow[n] = (float)dr; g_scol[n] = (float)dc; }
}

// ---------------- K2: global min/max partials over recomputed edge scores ----
__global__ void k_minmax_part(const int* __restrict__ ei, const float* __restrict__ b, int E){
  float b0 = b[0];
  float lmin = INFINITY, lmax = -INFINITY;
  for (int e = blockIdx.x*256 + threadIdx.x; e < E; e += gridDim.x*256){
    int r = ei[e], c = ei[E + e];
    float s = (g_srow[r] + g_scol[c]) + b0;
    lmin = fminf(lmin, s); lmax = fmaxf(lmax, s);
  }
  __shared__ float smin[256], smax[256];
  smin[threadIdx.x] = lmin; smax[threadIdx.x] = lmax;
  __syncthreads();
  for (int st = 128; st; st >>= 1){
    if (threadIdx.x < st){
      smin[threadIdx.x] = fminf(smin[threadIdx.x], smin[threadIdx.x+st]);
      smax[threadIdx.x] = fmaxf(smax[threadIdx.x], smax[threadIdx.x+st]);
    }
    __syncthreads();
  }
  if (threadIdx.x == 0){ g_pmin[blockIdx.x] = smin[0]; g_pmax[blockIdx.x] = smax[0]; }
}

// ---------------- K3: reduce partials ----------------
__global__ void k_minmax_final(int nb){
  float lmin = INFINITY, lmax = -INFINITY;
  for (int i = threadIdx.x; i < nb; i += 256){
    lmin = fminf(lmin, g_pmin[i]); lmax = fmaxf(lmax, g_pmax[i]);
  }
  __shared__ float smin[256], smax[256];
  smin[threadIdx.x] = lmin; smax[threadIdx.x] = lmax;
  __syncthreads();
  for (int st = 128; st; st >>= 1){
    if (threadIdx.x < st){
      smin[threadIdx.x] = fminf(smin[threadIdx.x], smin[threadIdx.x+st]);
      smax[threadIdx.x] = fmaxf(smax[threadIdx.x], smax[threadIdx.x+st]);
    }
    __syncthreads();
  }
  if (threadIdx.x == 0){ g_fmm[0] = smin[0]; g_fmm[1] = smax[0]; }
}

// ---------------- K4: per-graph stable top-k via RADIX SELECT ---------------
// key32 = ~orderable(norm): ascending key == descending norm, bitwise-identical
// construction to the reference's f32 norm. Stability by original index falls
// out of: keep (key < T) plus the first (k - count(key<T)) edges with key==T
// in index order — exactly jnp.argsort(-norm)[:k] stable semantics.
__global__ __launch_bounds__(256) void k_topk(const int* __restrict__ ei,
    const float* __restrict__ b, int E, int EPG, int k){
  __shared__ u32 keys[EPGMAX];
  __shared__ int hist[256];
  __shared__ int scan[256];
  __shared__ u32 sh_prefix;
  __shared__ int sh_rem, sh_rem_next, sh_digit;
  int g = blockIdx.x, tid = threadIdx.x;
  long long base = (long long)g * EPG;
  float b0 = b[0];
  float fmin = g_fmm[0], fmax = g_fmm[1];
  float denom = (fmax - fmin) + 1e-12f;
  float gf = (float)g;

  for (int i = tid; i < EPG; i += 256){
    long long e = base + i;
    int r = ei[e], c = ei[E + e];
    float s = (g_srow[r] + g_scol[c]) + b0;  // same f32 expr everywhere
    float frac = (s - fmin) / denom;         // f32 divide, as reference
    float nk = frac - gf;                    // f32 subtract -> same quantization
    u32 u = __float_as_uint(nk);
    u = (u & 0x80000000u) ? ~u : (u | 0x80000000u);  // orderable ascending
    keys[i] = ~u;                                    // descending norm
  }
  if (tid == 0){ sh_prefix = 0; sh_rem = k; }
  __syncthreads();

  // 4 radix rounds (8-bit digits, MSB first): find T = k-th smallest key
  for (int shift = 24; shift >= 0; shift -= 8){
    hist[tid] = 0;
    __syncthreads();
    u32 pref = sh_prefix;
    for (int i = tid; i < EPG; i += 256){
      u32 kk = keys[i];
      bool cand = (shift == 24) ? true : ((kk >> (shift + 8)) == pref);
      if (cand) atomicAdd(&hist[(kk >> shift) & 0xFF], 1);
    }
    __syncthreads();
    int v = hist[tid];
    scan[tid] = v;
    __syncthreads();
    for (int st = 1; st < 256; st <<= 1){
      int t2 = (tid >= st) ? scan[tid - st] : 0;
      __syncthreads();
      scan[tid] += t2;
      __syncthreads();
    }
    int rem = sh_rem;
    int cumprev = tid ? scan[tid - 1] : 0;
    if (cumprev < rem && rem <= scan[tid]){   // unique tid (hist[tid]>0 required)
      sh_digit = tid;
      sh_rem_next = rem - cumprev;
    }
    __syncthreads();
    if (tid == 0){
      sh_prefix = (sh_prefix << 8) | (u32)sh_digit;
      sh_rem = sh_rem_next;
    }
    __syncthreads();
  }
  u32 T = sh_prefix;
  int r_budget = sh_rem;   // = k - count(key < T), >= 1

  // tie ranks in index order: contiguous chunk per thread + exclusive scan
  int CH = (EPG + 255) / 256;
  int c0 = tid * CH;
  int cnt = 0;
  for (int j = 0; j < CH; j++){
    int i = c0 + j;
    if (i < EPG && keys[i] == T) cnt++;
  }
  scan[tid] = cnt;
  __syncthreads();
  for (int st = 1; st < 256; st <<= 1){
    int t2 = (tid >= st) ? scan[tid - st] : 0;
    __syncthreads();
    scan[tid] += t2;
    __syncthreads();
  }
  int rank = tid ? scan[tid - 1] : 0;

  for (int j = 0; j < CH; j++){
    int i = c0 + j;
    if (i >= EPG) break;
    u32 kk = keys[i];
    int kept;
    if (kk < T) kept = 1;
    else if (kk == T){ kept = (rank < r_budget); rank++; }
    else kept = 0;
    long long e = base + i;
    int rr = ei[e], cc = ei[E + e];
    g_mask[e] = (u8)kept;
    if (kept){ g_selC[rr] = 1; g_selC[cc] = 1; }
    else     { g_selF[rr] = 1; g_selF[cc] = 1; }
  }
}

// ---------------- K5: per-1024-node block sums of sel flags ----------------
__global__ void k_blocksum(int N){
  int bb = blockIdx.x, tid = threadIdx.x;
  int start = bb*1024;
  int c = 0, f = 0;
  #pragma unroll
  for (int q = 0; q < 4; q++){
    int n = start + tid*4 + q;
    if (n < N){ c += g_selC[n]; f += g_selF[n]; }
  }
  __shared__ int sc[256], sf[256];
  sc[tid] = c; sf[tid] = f;
  __syncthreads();
  for (int st = 128; st; st >>= 1){
    if (tid < st){ sc[tid] += sc[tid+st]; sf[tid] += sf[tid+st]; }
    __syncthreads();
  }
  if (tid == 0){ g_blkC[bb] = sc[0]; g_blkF[bb] = sf[0]; }
}

// ---------------- K6: serial scan of block sums + counts out ----------------
__global__ void k_scanblk(int nb, float* __restrict__ out, long long oNC, long long oNF){
  if (blockIdx.x == 0 && threadIdx.x == 0){
    int accC = 0, accF = 0;
    for (int i = 0; i < nb; i++){
      int c = g_blkC[i], f = g_blkF[i];
      g_blkC[i] = accC; g_blkF[i] = accF;
      accC += c; accF += f;
    }
    g_tot[0] = accC; g_tot[1] = accF;
    out[oNC] = (float)accC;
    out[oNF] = (float)accF;
  }
}

// ---------------- K7: dest permutation + batch outputs ----------------
__global__ void k_dest(const int* __restrict__ batch,
    float* __restrict__ out, long long oCB, long long oFB, int N){
  int bb = blockIdx.x, tid = threadIdx.x;
  int start = bb*1024;
  int idx0 = start + tid*4;
  int c[4], f[4]; int sc = 0, sf = 0;
  #pragma unroll
  for (int q = 0; q < 4; q++){
    int n = idx0 + q;
    int vc = (n < N) ? (int)g_selC[n] : 0;
    int vf = (n < N) ? (int)g_selF[n] : 0;
    c[q] = vc; f[q] = vf; sc += vc; sf += vf;
  }
  __shared__ int xc[256], xf[256];
  xc[tid] = sc; xf[tid] = sf;
  __syncthreads();
  for (int st = 1; st < 256; st <<= 1){
    int ac = (tid >= st) ? xc[tid-st] : 0;
    int af = (tid >= st) ? xf[tid-st] : 0;
    __syncthreads();
    xc[tid] += ac; xf[tid] += af;
    __syncthreads();
  }
  int excC = ((tid ? xc[tid-1] : 0)) + g_blkC[bb];
  int excF = ((tid ? xf[tid-1] : 0)) + g_blkF[bb];
  int nC = g_tot[0], nF = g_tot[1];
  int runC = 0, runF = 0;
  #pragma unroll
  for (int q = 0; q < 4; q++){
    int n = idx0 + q;
    if (n >= N) break;
    runC += c[q]; runF += f[q];
    int cumC = excC + runC;   // inclusive selected count through n
    int cumF = excF + runF;
    int dC = c[q] ? (cumC - 1) : (nC + (n - cumC));
    int dF = f[q] ? (cumF - 1) : (nF + (n - cumF));
    dC = min(max(dC, 0), N-1);  // firewall
    dF = min(max(dF, 0), N-1);
    g_destC[n] = dC; g_destF[n] = dF;
    float bt = (float)batch[n];
    out[oCB + dC] = c[q] ? bt : -1.0f;
    out[oFB + dF] = f[q] ? bt : -1.0f;
  }
}

// ---------------- K8: edge outputs (all f32) ----------------
__global__ void k_edges_out(const int* __restrict__ ei, const float* __restrict__ b,
    float* __restrict__ out, long long oCE, long long oCW, long long oFE, long long oFW,
    long long oS, long long oM, int E){
  int e = blockIdx.x*256 + threadIdx.x;
  if (e >= E) return;
  int r = ei[e], c = ei[E + e];
  float s = (g_srow[r] + g_scol[c]) + b[0];
  int m = g_mask[e];
  out[oCE + e]     = m ? (float)g_destC[r] : -1.0f;
  out[oCE + E + e] = m ? (float)g_destC[c] : -1.0f;
  out[oCW + e]     = m ? s : 0.0f;
  out[oFE + e]     = m ? -1.0f : (float)g_destF[r];
  out[oFE + E + e] = m ? -1.0f : (float)g_destF[c];
  out[oFW + e]     = m ? 0.0f : -s;
  out[oS + e]      = s;
  out[oM + e]      = m ? 1.0f : 0.0f;
}

// ---------------- K9: x permutation scatter (f32 passthrough) ----------------
__global__ void k_x_out(const float* __restrict__ x, float* __restrict__ out,
    long long oCX, long long oFX, int N){
  long long t = (long long)blockIdx.x*256 + threadIdx.x;
  if (t >= (long long)N*64) return;
  int n = (int)(t >> 6), cq = (int)(t & 63);
  float4 v = ((const float4*)x)[(long long)n*64 + cq];
  int dC = g_destC[n], dF = g_destF[n];
  long long iC = oCX + (long long)dC*DHID + cq*4;   // oCX==0 -> 16B aligned
  *reinterpret_cast<float4*>(out + iC) = v;
  long long iF = oFX + (long long)dF*DHID + cq*4;   // odd base -> scalar stores
  out[iF+0] = v.x; out[iF+1] = v.y; out[iF+2] = v.z; out[iF+3] = v.w;
}

extern "C" void kernel_launch(void* const* d_in, const int* in_sizes, int n_in,
                              void* d_out, int out_size, void* d_ws, size_t ws_size,
                              hipStream_t stream) {
  const float* x   = (const float*)d_in[0];
  const int* ei    = (const int*)d_in[1];
  const int* batch = (const int*)d_in[2];
  const float* W   = (const float*)d_in[3];
  const float* b   = (const float*)d_in[4];
  float* out = (float*)d_out;

  int N   = in_sizes[0] / DHID;   // 100000
  int E   = in_sizes[1] / 2;      // 3200000
  if (N > NMAX) N = NMAX;
  if (E > EMAX) E = EMAX;
  const int G   = N / 200;              // 500
  int EPG = (G > 0) ? E / G : 0;        // 6400
  if (EPG > EPGMAX) EPG = EPGMAX;
  const int k   = (int)ceilf(0.8f * (float)EPG);  // 5120 (f32 semantics match ref)

  // ---- output offsets (f32 elements, reference return order) ----
  long long oCX = 0;
  long long oCE = oCX + (long long)N*DHID;  // 25,600,000
  long long oCW = oCE + 2LL*E;              // 32,000,000
  long long oCB = oCW + E;                  // 35,200,000
  long long oNC = oCB + N;                  // 35,300,000
  long long oFX = oNC + 1;                  // 35,300,001
  long long oFE = oFX + (long long)N*DHID;  // 60,900,001
  long long oFW = oFE + 2LL*E;              // 67,300,001
  long long oFB = oFW + E;                  // 70,500,001
  long long oNF = oFB + N;                  // 70,600,001
  long long oS  = oNF + 1;                  // 70,600,002
  long long oM  = oS + E;                   // 73,800,002

  k_zero<<<(N + 255)/256, 256, 0, stream>>>(N);
  k_node_scores<<<(N + 3)/4, 256, 0, stream>>>(x, W, N);
  k_minmax_part<<<1024, 256, 0, stream>>>(ei, b, E);
  k_minmax_final<<<1, 256, 0, stream>>>(1024);
  k_topk<<<G, 256, 0, stream>>>(ei, b, E, EPG, k);
  int nblk = (N + 1023)/1024;
  k_blocksum<<<nblk, 256, 0, stream>>>(N);
  k_scanblk<<<1, 64, 0, stream>>>(nblk, out, oNC, oNF);
  k_dest<<<nblk, 256, 0, stream>>>(batch, out, oCB, oFB, N);
  k_edges_out<<<(E + 255)/256, 256, 0, stream>>>(ei, b, out, oCE, oCW, oFE, oFW, oS, oM, E);
  k_x_out<<<(int)(((long long)N*64 + 255)/256), 256, 0, stream>>>(x, out, oCX, oFX, N);
}

// Round 6
// 195.052 us; speedup vs baseline: 2.5174x; 1.1885x over previous
//
#include <hip/hip_runtime.h>
#include <cmath>

typedef unsigned long long u64;
typedef unsigned int u32;
typedef unsigned char u8;

#define DHID 256
#define NMAX 100000
#define EMAX 3200000
#define EPGMAX 6400
#define NBLKMAX 128
#define TOPK_T 512

// -------- all scratch as device globals: d_ws is NOT used --------
__device__ float g_srow[NMAX];
__device__ float g_scol[NMAX];
__device__ float g_escore[EMAX];
__device__ int   g_destC[NMAX];
__device__ int   g_destF[NMAX];
__device__ u8    g_selC[NMAX];
__device__ u8    g_selF[NMAX];
__device__ u8    g_mask[EMAX];
__device__ float g_pmin[1024];
__device__ float g_pmax[1024];
__device__ float g_fmm[2];
__device__ int   g_blkC[NBLKMAX];
__device__ int   g_blkF[NBLKMAX];
__device__ int   g_tot[2];

// ---------------- K1: per-node scores (wave per node, f64 accum) + sel zero --
__global__ void k_node_scores(const float* __restrict__ x, const float* __restrict__ W, int N){
  int t = blockIdx.x*256 + threadIdx.x;
  if (t < N){ g_selC[t] = 0; g_selF[t] = 0; }   // fused zeroing (pre-topk)
  int lane = threadIdx.x & 63, wave = threadIdx.x >> 6;
  int n = blockIdx.x*4 + wave;
  if (n >= N) return;
  float4 xv = ((const float4*)(x + (size_t)n*DHID))[lane];
  float4 wr = ((const float4*)W)[lane];
  float4 wc = ((const float4*)W)[64 + lane];
  double dr = (double)xv.x*wr.x + (double)xv.y*wr.y + (double)xv.z*wr.z + (double)xv.w*wr.w;
  double dc = (double)xv.x*wc.x + (double)xv.y*wc.y + (double)xv.z*wc.z + (double)xv.w*wc.w;
  #pragma unroll
  for (int off = 32; off; off >>= 1){
    dr += __shfl_xor(dr, off);
    dc += __shfl_xor(dc, off);
  }
  if (lane == 0){ g_srow[n] = (float)dr; g_scol[n] = (float)dc; }
}

// ---------------- K2: edge scores (stored) + global min/max partials --------
__global__ void k_minmax_part(const int* __restrict__ ei, const float* __restrict__ b, int E){
  float b0 = b[0];
  float lmin = INFINITY, lmax = -INFINITY;
  for (int e = blockIdx.x*256 + threadIdx.x; e < E; e += gridDim.x*256){
    int r = ei[e], c = ei[E + e];
    float s = (g_srow[r] + g_scol[c]) + b0;
    g_escore[e] = s;
    lmin = fminf(lmin, s); lmax = fmaxf(lmax, s);
  }
  __shared__ float smin[256], smax[256];
  smin[threadIdx.x] = lmin; smax[threadIdx.x] = lmax;
  __syncthreads();
  for (int st = 128; st; st >>= 1){
    if (threadIdx.x < st){
      smin[threadIdx.x] = fminf(smin[threadIdx.x], smin[threadIdx.x+st]);
      smax[threadIdx.x] = fmaxf(smax[threadIdx.x], smax[threadIdx.x+st]);
    }
    __syncthreads();
  }
  if (threadIdx.x == 0){ g_pmin[blockIdx.x] = smin[0]; g_pmax[blockIdx.x] = smax[0]; }
}

// ---------------- K3: reduce partials ----------------
__global__ void k_minmax_final(int nb){
  float lmin = INFINITY, lmax = -INFINITY;
  for (int i = threadIdx.x; i < nb; i += 256){
    lmin = fminf(lmin, g_pmin[i]); lmax = fmaxf(lmax, g_pmax[i]);
  }
  __shared__ float smin[256], smax[256];
  smin[threadIdx.x] = lmin; smax[threadIdx.x] = lmax;
  __syncthreads();
  for (int st = 128; st; st >>= 1){
    if (threadIdx.x < st){
      smin[threadIdx.x] = fminf(smin[threadIdx.x], smin[threadIdx.x+st]);
      smax[threadIdx.x] = fmaxf(smax[threadIdx.x], smax[threadIdx.x+st]);
    }
    __syncthreads();
  }
  if (threadIdx.x == 0){ g_fmm[0] = smin[0]; g_fmm[1] = smax[0]; }
}

// ---------------- K4: per-graph stable top-k via RADIX SELECT ---------------
// key32 = ~orderable(norm): ascending key == descending norm, bitwise-identical
// to the reference's f32 norm. Keep (key<T) plus first (k-count(key<T)) edges
// with key==T in index order == jnp.argsort(-norm)[:k] stable semantics.
__global__ __launch_bounds__(TOPK_T) void k_topk(const int* __restrict__ ei,
    int E, int EPG, int k){
  __shared__ u32 keys[EPGMAX];
  __shared__ int hist[256];
  __shared__ int scan[256];
  __shared__ int tscan[TOPK_T];
  __shared__ u32 sh_prefix;
  __shared__ int sh_rem, sh_rem_next, sh_digit;
  int g = blockIdx.x, tid = threadIdx.x;
  long long base = (long long)g * EPG;
  float fmin = g_fmm[0], fmax = g_fmm[1];
  float denom = (fmax - fmin) + 1e-12f;
  float gf = (float)g;

  for (int i = tid; i < EPG; i += TOPK_T){
    float s = g_escore[base + i];
    float frac = (s - fmin) / denom;         // f32 divide, as reference
    float nk = frac - gf;                    // f32 subtract -> same quantization
    u32 u = __float_as_uint(nk);
    u = (u & 0x80000000u) ? ~u : (u | 0x80000000u);  // orderable ascending
    keys[i] = ~u;                                    // descending norm
  }
  if (tid == 0){ sh_prefix = 0; sh_rem = k; }
  __syncthreads();

  // 4 radix rounds (8-bit digits, MSB first): find T = k-th smallest key
  for (int shift = 24; shift >= 0; shift -= 8){
    if (tid < 256) hist[tid] = 0;
    __syncthreads();
    u32 pref = sh_prefix;
    int lane = tid & 63;
    for (int i = tid; i < EPG; i += TOPK_T){
      u32 kk = keys[i];
      bool cand = (shift == 24) || ((kk >> (shift + 8)) == pref);
      if (cand){
        u32 digit = (kk >> shift) & 0xFF;
        u32 d0 = __builtin_amdgcn_readfirstlane(digit);
        if (__all(digit == d0)){
          // skew fast-path: whole active wave shares the digit
          u64 m = __ballot(1);
          if (lane == __builtin_ctzll(m)) atomicAdd(&hist[d0], (int)__popcll(m));
        } else {
          atomicAdd(&hist[digit], 1);
        }
      }
    }
    __syncthreads();
    if (tid < 256) scan[tid] = hist[tid];
    __syncthreads();
    for (int st = 1; st < 256; st <<= 1){
      int t2 = (tid < 256 && tid >= st) ? scan[tid - st] : 0;
      __syncthreads();
      if (tid < 256) scan[tid] += t2;
      __syncthreads();
    }
    if (tid < 256){
      int rem = sh_rem;
      int cumprev = tid ? scan[tid - 1] : 0;
      if (cumprev < rem && rem <= scan[tid]){   // unique tid with hist[tid]>0
        sh_digit = tid;
        sh_rem_next = rem - cumprev;
      }
    }
    __syncthreads();
    if (tid == 0){
      sh_prefix = (sh_prefix << 8) | (u32)sh_digit;
      sh_rem = sh_rem_next;
    }
    __syncthreads();
  }
  u32 T = sh_prefix;
  int r_budget = sh_rem;   // = k - count(key < T), >= 1

  // tie ranks in index order: contiguous chunk per thread + exclusive scan
  int CH = (EPG + TOPK_T - 1) / TOPK_T;
  int c0 = tid * CH;
  int cnt = 0;
  for (int j = 0; j < CH; j++){
    int i = c0 + j;
    if (i < EPG && keys[i] == T) cnt++;
  }
  tscan[tid] = cnt;
  __syncthreads();
  for (int st = 1; st < TOPK_T; st <<= 1){
    int t2 = (tid >= st) ? tscan[tid - st] : 0;
    __syncthreads();
    tscan[tid] += t2;
    __syncthreads();
  }
  int rank = tid ? tscan[tid - 1] : 0;

  for (int j = 0; j < CH; j++){
    int i = c0 + j;
    if (i >= EPG) break;
    u32 kk = keys[i];
    int kept;
    if (kk < T) kept = 1;
    else if (kk == T){ kept = (rank < r_budget); rank++; }
    else kept = 0;
    long long e = base + i;
    int rr = ei[e], cc = ei[E + e];
    g_mask[e] = (u8)kept;
    if (kept){ g_selC[rr] = 1; g_selC[cc] = 1; }
    else     { g_selF[rr] = 1; g_selF[cc] = 1; }
  }
}

// ---------------- K5: per-1024-node block sums of sel flags ----------------
__global__ void k_blocksum(int N){
  int bb = blockIdx.x, tid = threadIdx.x;
  int start = bb*1024;
  int c = 0, f = 0;
  #pragma unroll
  for (int q = 0; q < 4; q++){
    int n = start + tid*4 + q;
    if (n < N){ c += g_selC[n]; f += g_selF[n]; }
  }
  __shared__ int sc[256], sf[256];
  sc[tid] = c; sf[tid] = f;
  __syncthreads();
  for (int st = 128; st; st >>= 1){
    if (tid < st){ sc[tid] += sc[tid+st]; sf[tid] += sf[tid+st]; }
    __syncthreads();
  }
  if (tid == 0){ g_blkC[bb] = sc[0]; g_blkF[bb] = sf[0]; }
}

// ---------------- K6: serial scan of block sums + counts out ----------------
__global__ void k_scanblk(int nb, float* __restrict__ out, long long oNC, long long oNF){
  if (blockIdx.x == 0 && threadIdx.x == 0){
    int accC = 0, accF = 0;
    for (int i = 0; i < nb; i++){
      int c = g_blkC[i], f = g_blkF[i];
      g_blkC[i] = accC; g_blkF[i] = accF;
      accC += c; accF += f;
    }
    g_tot[0] = accC; g_tot[1] = accF;
    out[oNC] = (float)accC;
    out[oNF] = (float)accF;
  }
}

// ---------------- K7: dest permutation + batch outputs ----------------
__global__ void k_dest(const int* __restrict__ batch,
    float* __restrict__ out, long long oCB, long long oFB, int N){
  int bb = blockIdx.x, tid = threadIdx.x;
  int start = bb*1024;
  int idx0 = start + tid*4;
  int c[4], f[4]; int sc = 0, sf = 0;
  #pragma unroll
  for (int q = 0; q < 4; q++){
    int n = idx0 + q;
    int vc = (n < N) ? (int)g_selC[n] : 0;
    int vf = (n < N) ? (int)g_selF[n] : 0;
    c[q] = vc; f[q] = vf; sc += vc; sf += vf;
  }
  __shared__ int xc[256], xf[256];
  xc[tid] = sc; xf[tid] = sf;
  __syncthreads();
  for (int st = 1; st < 256; st <<= 1){
    int ac = (tid >= st) ? xc[tid-st] : 0;
    int af = (tid >= st) ? xf[tid-st] : 0;
    __syncthreads();
    xc[tid] += ac; xf[tid] += af;
    __syncthreads();
  }
  int excC = ((tid ? xc[tid-1] : 0)) + g_blkC[bb];
  int excF = ((tid ? xf[tid-1] : 0)) + g_blkF[bb];
  int nC = g_tot[0], nF = g_tot[1];
  int runC = 0, runF = 0;
  #pragma unroll
  for (int q = 0; q < 4; q++){
    int n = idx0 + q;
    if (n >= N) break;
    runC += c[q]; runF += f[q];
    int cumC = excC + runC;   // inclusive selected count through n
    int cumF = excF + runF;
    int dC = c[q] ? (cumC - 1) : (nC + (n - cumC));
    int dF = f[q] ? (cumF - 1) : (nF + (n - cumF));
    dC = min(max(dC, 0), N-1);  // firewall
    dF = min(max(dF, 0), N-1);
    g_destC[n] = dC; g_destF[n] = dF;
    float bt = (float)batch[n];
    out[oCB + dC] = c[q] ? bt : -1.0f;
    out[oFB + dF] = f[q] ? bt : -1.0f;
  }
}

// ---------------- K8: edge outputs (all f32) ----------------
__global__ void k_edges_out(const int* __restrict__ ei, const float* __restrict__ b,
    float* __restrict__ out, long long oCE, long long oCW, long long oFE, long long oFW,
    long long oS, long long oM, int E){
  int e = blockIdx.x*256 + threadIdx.x;
  if (e >= E) return;
  int r = ei[e], c = ei[E + e];
  float s = (g_srow[r] + g_scol[c]) + b[0];
  int m = g_mask[e];
  out[oCE + e]     = m ? (float)g_destC[r] : -1.0f;
  out[oCE + E + e] = m ? (float)g_destC[c] : -1.0f;
  out[oCW + e]     = m ? s : 0.0f;
  out[oFE + e]     = m ? -1.0f : (float)g_destF[r];
  out[oFE + E + e] = m ? -1.0f : (float)g_destF[c];
  out[oFW + e]     = m ? 0.0f : -s;
  out[oS + e]      = s;
  out[oM + e]      = m ? 1.0f : 0.0f;
}

// ---------------- K9: x permutation scatter (f32 passthrough) ----------------
__global__ void k_x_out(const float* __restrict__ x, float* __restrict__ out,
    long long oCX, long long oFX, int N){
  long long t = (long long)blockIdx.x*256 + threadIdx.x;
  if (t >= (long long)N*64) return;
  int n = (int)(t >> 6), cq = (int)(t & 63);
  float4 v = ((const float4*)x)[(long long)n*64 + cq];
  int dC = g_destC[n], dF = g_destF[n];
  long long iC = oCX + (long long)dC*DHID + cq*4;   // oCX==0 -> 16B aligned
  *reinterpret_cast<float4*>(out + iC) = v;
  long long iF = oFX + (long long)dF*DHID + cq*4;   // odd base -> scalar stores
  out[iF+0] = v.x; out[iF+1] = v.y; out[iF+2] = v.z; out[iF+3] = v.w;
}

extern "C" void kernel_launch(void* const* d_in, const int* in_sizes, int n_in,
                              void* d_out, int out_size, void* d_ws, size_t ws_size,
                              hipStream_t stream) {
  const float* x   = (const float*)d_in[0];
  const int* ei    = (const int*)d_in[1];
  const int* batch = (const int*)d_in[2];
  const float* W   = (const float*)d_in[3];
  const float* b   = (const float*)d_in[4];
  float* out = (float*)d_out;

  int N   = in_sizes[0] / DHID;   // 100000
  int E   = in_sizes[1] / 2;      // 3200000
  if (N > NMAX) N = NMAX;
  if (E > EMAX) E = EMAX;
  const int G   = N / 200;              // 500
  int EPG = (G > 0) ? E / G : 0;        // 6400
  if (EPG > EPGMAX) EPG = EPGMAX;
  const int k   = (int)ceilf(0.8f * (float)EPG);  // 5120 (f32 semantics match ref)

  // ---- output offsets (f32 elements, reference return order) ----
  long long oCX = 0;
  long long oCE = oCX + (long long)N*DHID;  // 25,600,000
  long long oCW = oCE + 2LL*E;              // 32,000,000
  long long oCB = oCW + E;                  // 35,200,000
  long long oNC = oCB + N;                  // 35,300,000
  long long oFX = oNC + 1;                  // 35,300,001
  long long oFE = oFX + (long long)N*DHID;  // 60,900,001
  long long oFW = oFE + 2LL*E;              // 67,300,001
  long long oFB = oFW + E;                  // 70,500,001
  long long oNF = oFB + N;                  // 70,600,001
  long long oS  = oNF + 1;                  // 70,600,002
  long long oM  = oS + E;                   // 73,800,002

  k_node_scores<<<(N + 3)/4, 256, 0, stream>>>(x, W, N);
  k_minmax_part<<<1024, 256, 0, stream>>>(ei, b, E);
  k_minmax_final<<<1, 256, 0, stream>>>(1024);
  k_topk<<<G, TOPK_T, 0, stream>>>(ei, E, EPG, k);
  int nblk = (N + 1023)/1024;
  k_blocksum<<<nblk, 256, 0, stream>>>(N);
  k_scanblk<<<1, 64, 0, stream>>>(nblk, out, oNC, oNF);
  k_dest<<<nblk, 256, 0, stream>>>(batch, out, oCB, oFB, N);
  k_edges_out<<<(E + 255)/256, 256, 0, stream>>>(ei, b, out, oCE, oCW, oFE, oFW, oS, oM, E);
  k_x_out<<<(int)(((long long)N*64 + 255)/256), 256, 0, stream>>>(x, out, oCX, oFX, N);
}

// Round 7
// 171.337 us; speedup vs baseline: 2.8659x; 1.1384x over previous
//
#include <hip/hip_runtime.h>
#include <cmath>

typedef unsigned long long u64;
typedef unsigned int u32;
typedef unsigned char u8;

#define DHID 256
#define NMAX 100000
#define EMAX 3200000
#define EPGMAX 6400
#define NBLKMAX 128
#define TOPK_T 512

// -------- all scratch as device globals: d_ws is NOT used --------
__device__ float g_srow[NMAX];
__device__ float g_scol[NMAX];
__device__ float g_escore[EMAX];
__device__ int   g_destC[NMAX];
__device__ int   g_destF[NMAX];
__device__ u8    g_selC[NMAX];
__device__ u8    g_selF[NMAX];
__device__ u8    g_mask[EMAX];
__device__ float g_pmin[1024];
__device__ float g_pmax[1024];
__device__ int   g_blkC[NBLKMAX];
__device__ int   g_blkF[NBLKMAX];
__device__ int   g_tot[2];

// ---------------- K1: per-node scores (wave per node, f64 accum) + sel zero --
__global__ void k_node_scores(const float* __restrict__ x, const float* __restrict__ W, int N){
  int t = blockIdx.x*256 + threadIdx.x;
  if (t < N){ g_selC[t] = 0; g_selF[t] = 0; }   // fused zeroing (pre-topk)
  int lane = threadIdx.x & 63, wave = threadIdx.x >> 6;
  int n = blockIdx.x*4 + wave;
  if (n >= N) return;
  float4 xv = ((const float4*)(x + (size_t)n*DHID))[lane];
  float4 wr = ((const float4*)W)[lane];
  float4 wc = ((const float4*)W)[64 + lane];
  double dr = (double)xv.x*wr.x + (double)xv.y*wr.y + (double)xv.z*wr.z + (double)xv.w*wr.w;
  double dc = (double)xv.x*wc.x + (double)xv.y*wc.y + (double)xv.z*wc.z + (double)xv.w*wc.w;
  #pragma unroll
  for (int off = 32; off; off >>= 1){
    dr += __shfl_xor(dr, off);
    dc += __shfl_xor(dc, off);
  }
  if (lane == 0){ g_srow[n] = (float)dr; g_scol[n] = (float)dc; }
}

// ---------------- K2: edge scores (stored) + global min/max partials --------
__global__ void k_minmax_part(const int* __restrict__ ei, const float* __restrict__ b, int E){
  float b0 = b[0];
  float lmin = INFINITY, lmax = -INFINITY;
  for (int e = blockIdx.x*256 + threadIdx.x; e < E; e += gridDim.x*256){
    int r = ei[e], c = ei[E + e];
    float s = (g_srow[r] + g_scol[c]) + b0;
    g_escore[e] = s;
    lmin = fminf(lmin, s); lmax = fmaxf(lmax, s);
  }
  __shared__ float smin[256], smax[256];
  smin[threadIdx.x] = lmin; smax[threadIdx.x] = lmax;
  __syncthreads();
  for (int st = 128; st; st >>= 1){
    if (threadIdx.x < st){
      smin[threadIdx.x] = fminf(smin[threadIdx.x], smin[threadIdx.x+st]);
      smax[threadIdx.x] = fmaxf(smax[threadIdx.x], smax[threadIdx.x+st]);
    }
    __syncthreads();
  }
  if (threadIdx.x == 0){ g_pmin[blockIdx.x] = smin[0]; g_pmax[blockIdx.x] = smax[0]; }
}

// ---------------- K3: per-graph stable top-k via RADIX SELECT ---------------
// key32 = ~orderable(norm): ascending key == descending norm, bitwise-identical
// to the reference's f32 norm. Keep (key<T) plus first (k-count(key<T)) edges
// with key==T in index order == jnp.argsort(-norm)[:k] stable semantics.
// Also: inlined global minmax reduction (prologue) and all dest-independent
// edge outputs (edge_score, mask, causal_w, conf_w) in the coalesced store pass.
__global__ __launch_bounds__(TOPK_T) void k_topk(const int* __restrict__ ei,
    float* __restrict__ out, long long oCW, long long oFW, long long oS, long long oM,
    int E, int EPG, int k){
  __shared__ u32 keys[EPGMAX];
  __shared__ u8  keep[EPGMAX];
  __shared__ int hist[256];
  __shared__ int scan[256];
  __shared__ int tscan[TOPK_T];
  __shared__ float redA[TOPK_T];
  __shared__ u32 sh_prefix;
  __shared__ int sh_rem, sh_rem_next, sh_digit;
  int g = blockIdx.x, tid = threadIdx.x;
  long long base = (long long)g * EPG;

  // prologue: reduce 1024 min/max partials (redundant per block, L2-hot)
  float lmin = fminf(g_pmin[tid], g_pmin[tid + 512]);
  float lmax = fmaxf(g_pmax[tid], g_pmax[tid + 512]);
  redA[tid] = lmin;
  __syncthreads();
  for (int st = 256; st; st >>= 1){
    if (tid < st) redA[tid] = fminf(redA[tid], redA[tid+st]);
    __syncthreads();
  }
  float fmin = redA[0];
  __syncthreads();
  redA[tid] = lmax;
  __syncthreads();
  for (int st = 256; st; st >>= 1){
    if (tid < st) redA[tid] = fmaxf(redA[tid], redA[tid+st]);
    __syncthreads();
  }
  float fmax = redA[0];
  __syncthreads();

  float denom = (fmax - fmin) + 1e-12f;
  float gf = (float)g;

  for (int i = tid; i < EPG; i += TOPK_T){
    float s = g_escore[base + i];
    float frac = (s - fmin) / denom;         // f32 divide, as reference
    float nk = frac - gf;                    // f32 subtract -> same quantization
    u32 u = __float_as_uint(nk);
    u = (u & 0x80000000u) ? ~u : (u | 0x80000000u);  // orderable ascending
    keys[i] = ~u;                                    // descending norm
  }
  if (tid == 0){ sh_prefix = 0; sh_rem = k; }
  __syncthreads();

  // 4 radix rounds (8-bit digits, MSB first): find T = k-th smallest key
  for (int shift = 24; shift >= 0; shift -= 8){
    if (tid < 256) hist[tid] = 0;
    __syncthreads();
    u32 pref = sh_prefix;
    int lane = tid & 63;
    for (int i = tid; i < EPG; i += TOPK_T){
      u32 kk = keys[i];
      bool cand = (shift == 24) || ((kk >> (shift + 8)) == pref);
      if (cand){
        u32 digit = (kk >> shift) & 0xFF;
        u32 d0 = __builtin_amdgcn_readfirstlane(digit);
        if (__all(digit == d0)){
          // skew fast-path: whole active wave shares the digit
          u64 m = __ballot(1);
          if (lane == __builtin_ctzll(m)) atomicAdd(&hist[d0], (int)__popcll(m));
        } else {
          atomicAdd(&hist[digit], 1);
        }
      }
    }
    __syncthreads();
    if (tid < 256) scan[tid] = hist[tid];
    __syncthreads();
    for (int st = 1; st < 256; st <<= 1){
      int t2 = (tid < 256 && tid >= st) ? scan[tid - st] : 0;
      __syncthreads();
      if (tid < 256) scan[tid] += t2;
      __syncthreads();
    }
    if (tid < 256){
      int rem = sh_rem;
      int cumprev = tid ? scan[tid - 1] : 0;
      if (cumprev < rem && rem <= scan[tid]){   // unique tid with hist[tid]>0
        sh_digit = tid;
        sh_rem_next = rem - cumprev;
      }
    }
    __syncthreads();
    if (tid == 0){
      sh_prefix = (sh_prefix << 8) | (u32)sh_digit;
      sh_rem = sh_rem_next;
    }
    __syncthreads();
  }
  u32 T = sh_prefix;
  int r_budget = sh_rem;   // = k - count(key < T), >= 1

  // tie ranks in index order: contiguous chunk per thread + exclusive scan
  int CH = (EPG + TOPK_T - 1) / TOPK_T;
  int c0 = tid * CH;
  int cnt = 0;
  for (int j = 0; j < CH; j++){
    int i = c0 + j;
    if (i < EPG && keys[i] == T) cnt++;
  }
  tscan[tid] = cnt;
  __syncthreads();
  for (int st = 1; st < TOPK_T; st <<= 1){
    int t2 = (tid >= st) ? tscan[tid - st] : 0;
    __syncthreads();
    tscan[tid] += t2;
    __syncthreads();
  }
  int rank = tid ? tscan[tid - 1] : 0;

  for (int j = 0; j < CH; j++){
    int i = c0 + j;
    if (i >= EPG) break;
    u32 kk = keys[i];
    int kept;
    if (kk < T) kept = 1;
    else if (kk == T){ kept = (rank < r_budget); rank++; }
    else kept = 0;
    keep[i] = (u8)kept;
  }
  __syncthreads();

  // store pass (strided -> all global streams coalesced)
  for (int i = tid; i < EPG; i += TOPK_T){
    long long e = base + i;
    int kept = keep[i];
    float s = g_escore[e];     // L2/L3-hot re-read
    int rr = ei[e], cc = ei[E + e];
    g_mask[e] = (u8)kept;
    out[oS + e]  = s;
    out[oM + e]  = kept ? 1.0f : 0.0f;
    out[oCW + e] = kept ? s : 0.0f;
    out[oFW + e] = kept ? 0.0f : -s;
    if (kept){ g_selC[rr] = 1; g_selC[cc] = 1; }
    else     { g_selF[rr] = 1; g_selF[cc] = 1; }
  }
}

// ---------------- K4: per-1024-node block sums of sel flags ----------------
__global__ void k_blocksum(int N){
  int bb = blockIdx.x, tid = threadIdx.x;
  int start = bb*1024;
  int c = 0, f = 0;
  #pragma unroll
  for (int q = 0; q < 4; q++){
    int n = start + tid*4 + q;
    if (n < N){ c += g_selC[n]; f += g_selF[n]; }
  }
  __shared__ int sc[256], sf[256];
  sc[tid] = c; sf[tid] = f;
  __syncthreads();
  for (int st = 128; st; st >>= 1){
    if (tid < st){ sc[tid] += sc[tid+st]; sf[tid] += sf[tid+st]; }
    __syncthreads();
  }
  if (tid == 0){ g_blkC[bb] = sc[0]; g_blkF[bb] = sf[0]; }
}

// ---------------- K5: parallel scan of block sums + counts out --------------
__global__ void k_scanblk(int nb, float* __restrict__ out, long long oNC, long long oNF){
  __shared__ int sC[NBLKMAX], sF[NBLKMAX];
  int tid = threadIdx.x;   // 128 threads
  int c = (tid < nb) ? g_blkC[tid] : 0;
  int f = (tid < nb) ? g_blkF[tid] : 0;
  sC[tid] = c; sF[tid] = f;
  __syncthreads();
  for (int st = 1; st < NBLKMAX; st <<= 1){
    int a  = (tid >= st) ? sC[tid - st] : 0;
    int b2 = (tid >= st) ? sF[tid - st] : 0;
    __syncthreads();
    sC[tid] += a; sF[tid] += b2;
    __syncthreads();
  }
  if (tid < nb){ g_blkC[tid] = sC[tid] - c; g_blkF[tid] = sF[tid] - f; }  // exclusive
  if (tid == NBLKMAX - 1){
    g_tot[0] = sC[NBLKMAX-1]; g_tot[1] = sF[NBLKMAX-1];
    out[oNC] = (float)sC[NBLKMAX-1];
    out[oNF] = (float)sF[NBLKMAX-1];
  }
}

// ---------------- K6: dest permutation + batch outputs ----------------
__global__ void k_dest(const int* __restrict__ batch,
    float* __restrict__ out, long long oCB, long long oFB, int N){
  int bb = blockIdx.x, tid = threadIdx.x;
  int start = bb*1024;
  int idx0 = start + tid*4;
  int c[4], f[4]; int sc = 0, sf = 0;
  #pragma unroll
  for (int q = 0; q < 4; q++){
    int n = idx0 + q;
    int vc = (n < N) ? (int)g_selC[n] : 0;
    int vf = (n < N) ? (int)g_selF[n] : 0;
    c[q] = vc; f[q] = vf; sc += vc; sf += vf;
  }
  __shared__ int xc[256], xf[256];
  xc[tid] = sc; xf[tid] = sf;
  __syncthreads();
  for (int st = 1; st < 256; st <<= 1){
    int ac = (tid >= st) ? xc[tid-st] : 0;
    int af = (tid >= st) ? xf[tid-st] : 0;
    __syncthreads();
    xc[tid] += ac; xf[tid] += af;
    __syncthreads();
  }
  int excC = ((tid ? xc[tid-1] : 0)) + g_blkC[bb];
  int excF = ((tid ? xf[tid-1] : 0)) + g_blkF[bb];
  int nC = g_tot[0], nF = g_tot[1];
  int runC = 0, runF = 0;
  #pragma unroll
  for (int q = 0; q < 4; q++){
    int n = idx0 + q;
    if (n >= N) break;
    runC += c[q]; runF += f[q];
    int cumC = excC + runC;   // inclusive selected count through n
    int cumF = excF + runF;
    int dC = c[q] ? (cumC - 1) : (nC + (n - cumC));
    int dF = f[q] ? (cumF - 1) : (nF + (n - cumF));
    dC = min(max(dC, 0), N-1);  // firewall
    dF = min(max(dF, 0), N-1);
    g_destC[n] = dC; g_destF[n] = dF;
    float bt = (float)batch[n];
    out[oCB + dC] = c[q] ? bt : -1.0f;
    out[oFB + dF] = f[q] ? bt : -1.0f;
  }
}

// ---------------- K7: edge-index outputs (dest-dependent only) --------------
__global__ void k_ei_out(const int* __restrict__ ei,
    float* __restrict__ out, long long oCE, long long oFE, int E){
  int e = blockIdx.x*256 + threadIdx.x;
  if (e >= E) return;
  int r = ei[e], c = ei[E + e];
  int m = g_mask[e];
  out[oCE + e]     = m ? (float)g_destC[r] : -1.0f;
  out[oCE + E + e] = m ? (float)g_destC[c] : -1.0f;
  out[oFE + e]     = m ? -1.0f : (float)g_destF[r];
  out[oFE + E + e] = m ? -1.0f : (float)g_destF[c];
}

// ---------------- K8: x permutation scatter (f32 passthrough) ----------------
__global__ void k_x_out(const float* __restrict__ x, float* __restrict__ out,
    long long oCX, long long oFX, int N){
  long long t = (long long)blockIdx.x*256 + threadIdx.x;
  if (t >= (long long)N*64) return;
  int n = (int)(t >> 6), cq = (int)(t & 63);
  float4 v = ((const float4*)x)[(long long)n*64 + cq];
  int dC = g_destC[n], dF = g_destF[n];
  long long iC = oCX + (long long)dC*DHID + cq*4;   // oCX==0 -> 16B aligned
  *reinterpret_cast<float4*>(out + iC) = v;
  long long iF = oFX + (long long)dF*DHID + cq*4;   // iF % 4 == 1 always
  out[iF] = v.x;
  float2 mid; mid.x = v.y; mid.y = v.z;
  *reinterpret_cast<float2*>(out + iF + 1) = mid;   // 8B-aligned
  out[iF + 3] = v.w;
}

extern "C" void kernel_launch(void* const* d_in, const int* in_sizes, int n_in,
                              void* d_out, int out_size, void* d_ws, size_t ws_size,
                              hipStream_t stream) {
  const float* x   = (const float*)d_in[0];
  const int* ei    = (const int*)d_in[1];
  const int* batch = (const int*)d_in[2];
  const float* W   = (const float*)d_in[3];
  const float* b   = (const float*)d_in[4];
  float* out = (float*)d_out;

  int N   = in_sizes[0] / DHID;   // 100000
  int E   = in_sizes[1] / 2;      // 3200000
  if (N > NMAX) N = NMAX;
  if (E > EMAX) E = EMAX;
  const int G   = N / 200;              // 500
  int EPG = (G > 0) ? E / G : 0;        // 6400
  if (EPG > EPGMAX) EPG = EPGMAX;
  const int k   = (int)ceilf(0.8f * (float)EPG);  // 5120 (f32 semantics match ref)

  // ---- output offsets (f32 elements, reference return order) ----
  long long oCX = 0;
  long long oCE = oCX + (long long)N*DHID;  // 25,600,000
  long long oCW = oCE + 2LL*E;              // 32,000,000
  long long oCB = oCW + E;                  // 35,200,000
  long long oNC = oCB + N;                  // 35,300,000
  long long oFX = oNC + 1;                  // 35,300,001
  long long oFE = oFX + (long long)N*DHID;  // 60,900,001
  long long oFW = oFE + 2LL*E;              // 67,300,001
  long long oFB = oFW + E;                  // 70,500,001
  long long oNF = oFB + N;                  // 70,600,001
  long long oS  = oNF + 1;                  // 70,600,002
  long long oM  = oS + E;                   // 73,800,002

  k_node_scores<<<(N + 3)/4, 256, 0, stream>>>(x, W, N);
  k_minmax_part<<<1024, 256, 0, stream>>>(ei, b, E);
  k_topk<<<G, TOPK_T, 0, stream>>>(ei, out, oCW, oFW, oS, oM, E, EPG, k);
  int nblk = (N + 1023)/1024;
  k_blocksum<<<nblk, 256, 0, stream>>>(N);
  k_scanblk<<<1, NBLKMAX, 0, stream>>>(nblk, out, oNC, oNF);
  k_dest<<<nblk, 256, 0, stream>>>(batch, out, oCB, oFB, N);
  k_ei_out<<<(E + 255)/256, 256, 0, stream>>>(ei, out, oCE, oFE, E);
  k_x_out<<<(int)(((long long)N*64 + 255)/256), 256, 0, stream>>>(x, out, oCX, oFX, N);
}